// Round 1
// baseline (208.826 us; speedup 1.0000x reference)
//
#include <hip/hip_runtime.h>
#include <hip/hip_bf16.h>

typedef unsigned short u16;
typedef unsigned int u32;

#define B_ 4
#define C_ 256
#define N_ 4096

// scale * log2(e) = (1/16) * 1.4426950408889634
constexpr float C1 = 0.09016844005556021f;

typedef float f32x16 __attribute__((ext_vector_type(16)));
typedef short bf16x8 __attribute__((ext_vector_type(8)));

__device__ __forceinline__ u16 bf16r(float f) {
    union { float f; u32 u; } a; a.f = f;
    u32 u = a.u;
    u += 0x7fffu + ((u >> 16) & 1u);   // RNE
    return (u16)(u >> 16);
}

__device__ __forceinline__ u32 pk2(float a, float b) {
    __hip_bfloat162 h = __float22bfloat162_rn(make_float2(a, b)); // x=low
    union { __hip_bfloat162 h; u32 u; } c; c.h = h;
    return c.u;
}

__device__ __forceinline__ bf16x8 ld8(const u16* p) {
    return *reinterpret_cast<const bf16x8*>(p);
}

__device__ __forceinline__ int crow(int r, int hi) { return (r & 3) + 8 * (r >> 2) + 4 * hi; }

// ---------------- prep: weight casts + BN fold ----------------
__global__ __launch_bounds__(256) void prep(
    const float* __restrict__ Wq, const float* __restrict__ Wk,
    const float* __restrict__ Wv, const float* __restrict__ Wo,
    const float* __restrict__ bo, const float* __restrict__ gamma,
    const float* __restrict__ beta, const float* __restrict__ rm, const float* __restrict__ rv,
    u16* __restrict__ wqk, u16* __restrict__ wv_b, u16* __restrict__ wo_b,
    float* __restrict__ scale, float* __restrict__ shift)
{
    int i = blockIdx.x * 256 + threadIdx.x;
    if (i < 16384) {
        float w = (i < 8192) ? Wq[i] * C1 : Wk[i - 8192];
        wqk[i] = bf16r(w);
    } else if (i < 81920) {
        wv_b[i - 16384] = bf16r(Wv[i - 16384]);
    } else if (i < 147456) {
        wo_b[i - 81920] = bf16r(Wo[i - 81920]);
    } else if (i < 147712) {
        int o = i - 147456;
        float inv = gamma[o] * rsqrtf(rv[o] + 1e-5f);
        scale[o] = inv;
        shift[o] = beta[o] + (bo[o] - rm[o]) * inv;
    }
}

// ---------------- xpose: x[b][c][n] f32 -> xbt[b][n][c] bf16 ----------------
__global__ __launch_bounds__(256) void xpose(const float* __restrict__ x, u16* __restrict__ xbt)
{
    __shared__ float t[64][65];
    int b = blockIdx.z, c0 = blockIdx.y * 64, n0 = blockIdx.x * 64;
    int tid = threadIdx.x;
    const float* xb = x + ((size_t)b * C_ + c0) * N_ + n0;
#pragma unroll
    for (int it = 0; it < 16; ++it) {
        int fl = it * 256 + tid; int cr = fl >> 6, nr = fl & 63;
        t[cr][nr] = xb[(size_t)cr * N_ + nr];
    }
    __syncthreads();
    u16* ob = xbt + ((size_t)b * N_ + n0) * C_ + c0;
#pragma unroll
    for (int it = 0; it < 8; ++it) {
        int sl = it * 256 + tid; int nr = sl >> 5, cp = sl & 31;
        u32 w = pk2(t[2 * cp][nr], t[2 * cp + 1][nr]);
        *reinterpret_cast<u32*>(ob + (size_t)nr * C_ + 2 * cp) = w;
    }
}

// ---------------- proj_qkv: qkt[b][n][64] (q|k), v[b][c][n] ----------------
__global__ __launch_bounds__(256) void proj_qkv(
    const u16* __restrict__ xbt, const u16* __restrict__ wqk, const u16* __restrict__ wv,
    const float* __restrict__ bq, const float* __restrict__ bk, const float* __restrict__ bv,
    u16* __restrict__ qkt, u16* __restrict__ vout)
{
    int lane = threadIdx.x & 63, wid = threadIdx.x >> 6;
    int r31 = lane & 31, hi = lane >> 5;
    int b = blockIdx.z, n0 = blockIdx.x * 64, mt = blockIdx.y;
    f32x16 acc;
#pragma unroll
    for (int r = 0; r < 16; ++r) acc[r] = 0.f;
    if (mt == 0) {
        int wn = wid >> 1, wo = wid & 1;
        const u16* ar = xbt + ((size_t)b * N_ + n0 + wn * 32 + r31) * C_ + hi * 8;
        const u16* br = wqk + (size_t)(wo * 32 + r31) * C_ + hi * 8;
#pragma unroll
        for (int ks = 0; ks < 16; ++ks)
            acc = __builtin_amdgcn_mfma_f32_32x32x16_bf16(ld8(ar + ks * 16), ld8(br + ks * 16), acc, 0, 0, 0);
        int o = wo * 32 + r31;
        float bias = (o < 32) ? bq[o] * C1 : bk[o - 32];
        u16* qrow = qkt + ((size_t)b * N_ + n0 + wn * 32) * 64 + o;
#pragma unroll
        for (int r = 0; r < 16; ++r)
            qrow[(size_t)crow(r, hi) * 64] = bf16r(acc[r] + bias);
    } else {
        int wc = wid >> 1, wn = wid & 1;
        int c0 = (mt - 1) * 64 + wc * 32;
        const u16* ar = wv + (size_t)(c0 + r31) * C_ + hi * 8;
        const u16* br = xbt + ((size_t)b * N_ + n0 + wn * 32 + r31) * C_ + hi * 8;
#pragma unroll
        for (int ks = 0; ks < 16; ++ks)
            acc = __builtin_amdgcn_mfma_f32_32x32x16_bf16(ld8(ar + ks * 16), ld8(br + ks * 16), acc, 0, 0, 0);
        int n = n0 + wn * 32 + r31;
        u16* vb = vout + (size_t)b * C_ * N_ + n;
#pragma unroll
        for (int r = 0; r < 16; ++r) {
            int c = c0 + crow(r, hi);
            vb[(size_t)c * N_] = bf16r(acc[r] + bv[c]);
        }
    }
}

// ---------------- attn: flash attention, out aot[b][n][c] bf16 ----------------
__global__ __launch_bounds__(256, 1) void attn(
    const u16* __restrict__ qkt, const u16* __restrict__ v, u16* __restrict__ aot)
{
    __shared__ float tls[4][32][33];
    int lane = threadIdx.x & 63, wid = threadIdx.x >> 6;
    int r31 = lane & 31, hi = lane >> 5;
    int b = blockIdx.y;
    int q0 = blockIdx.x * 64 + (wid >> 1) * 32;  // this warp's 32 query rows
    int ch = wid & 1;                            // c-half (128 channels)
    const u16* qkb = qkt + (size_t)b * N_ * 64;
    const u16* vb  = v + (size_t)b * C_ * N_ + (size_t)(ch * 128 + r31) * N_;

    // Q as B-operand fragments (col = own qp = lane&31), 2 K=16 steps over d=32
    bf16x8 qf0 = ld8(qkb + (size_t)(q0 + r31) * 64 + hi * 8);
    bf16x8 qf1 = ld8(qkb + (size_t)(q0 + r31) * 64 + 16 + hi * 8);

    f32x16 acc[4];
#pragma unroll
    for (int ct = 0; ct < 4; ++ct)
#pragma unroll
        for (int r = 0; r < 16; ++r) acc[ct][r] = 0.f;

    f32x16 z;
#pragma unroll
    for (int r = 0; r < 16; ++r) z[r] = 0.f;

    float m_run = -INFINITY, l_run = 0.f;

    for (int kt = 0; kt < 64; ++kt) {
        int k0 = kt * 64;
        // S'[kp][qp] = sum_d K[kp][d] * Q[d][qp]  (logits already in exp2 domain via C1)
        const u16* kb = qkb + (size_t)(k0 + r31) * 64 + 32 + hi * 8;
        f32x16 s0 = __builtin_amdgcn_mfma_f32_32x32x16_bf16(ld8(kb), qf0, z, 0, 0, 0);
        s0 = __builtin_amdgcn_mfma_f32_32x32x16_bf16(ld8(kb + 16), qf1, s0, 0, 0, 0);
        f32x16 s1 = __builtin_amdgcn_mfma_f32_32x32x16_bf16(ld8(kb + 32 * 64), qf0, z, 0, 0, 0);
        s1 = __builtin_amdgcn_mfma_f32_32x32x16_bf16(ld8(kb + 32 * 64 + 16), qf1, s1, 0, 0, 0);

        // issue V fragment loads early (hide L2 latency under softmax VALU)
        bf16x8 vf[4][4];
#pragma unroll
        for (int ct = 0; ct < 4; ++ct)
#pragma unroll
            for (int kc = 0; kc < 4; ++kc)
                vf[ct][kc] = ld8(vb + (size_t)(ct * 32) * N_ + k0 + kc * 16 + hi * 8);

        // lane-local softmax for own row qp = lane&31 (own 32 kp + partner 32 kp)
        float pmax = -INFINITY;
#pragma unroll
        for (int r = 0; r < 16; ++r) { pmax = fmaxf(pmax, s0[r]); pmax = fmaxf(pmax, s1[r]); }
        pmax = fmaxf(pmax, __shfl_xor(pmax, 32));
        float m_new = fmaxf(m_run, pmax);
        float f = exp2f(m_run - m_new);
        float p[2][16];
        float ps = 0.f;
#pragma unroll
        for (int r = 0; r < 16; ++r) {
            float e0 = exp2f(s0[r] - m_new);
            float e1 = exp2f(s1[r] - m_new);
            p[0][r] = e0; p[1][r] = e1; ps += e0 + e1;
        }
        ps += __shfl_xor(ps, 32);
        l_run = l_run * f + ps;
        m_run = m_new;
#pragma unroll
        for (int ct = 0; ct < 4; ++ct) acc[ct] = acc[ct] * f;

        // repack P -> PV B-fragment (lane holds P[own qp][16kc + 8hi + j])
        bf16x8 pf[4];
#pragma unroll
        for (int kc = 0; kc < 4; ++kc) {
            int t = kc >> 1, c16 = kc & 1;
            u32 w0 = pk2(p[t][8 * c16 + 0], p[t][8 * c16 + 1]);
            u32 w1 = pk2(p[t][8 * c16 + 2], p[t][8 * c16 + 3]);
            u32 w2 = pk2(p[t][8 * c16 + 4], p[t][8 * c16 + 5]);
            u32 w3 = pk2(p[t][8 * c16 + 6], p[t][8 * c16 + 7]);
            u32 w0s = __shfl_xor(w0, 32);
            u32 w1s = __shfl_xor(w1, 32);
            u32 w2s = __shfl_xor(w2, 32);
            u32 w3s = __shfl_xor(w3, 32);
            union { bf16x8 f8; u32 u[4]; } fu;
            fu.u[0] = hi ? w2s : w0;
            fu.u[1] = hi ? w3s : w1;
            fu.u[2] = hi ? w2 : w0s;
            fu.u[3] = hi ? w3 : w1s;
            pf[kc] = fu.f8;
        }

        // O'[c][qp] += V[c][k] * P^T  (cols = own qp -> rescale stays lane-local)
#pragma unroll
        for (int ct = 0; ct < 4; ++ct)
#pragma unroll
            for (int kc = 0; kc < 4; ++kc)
                acc[ct] = __builtin_amdgcn_mfma_f32_32x32x16_bf16(vf[ct][kc], pf[kc], acc[ct], 0, 0, 0);
    }

    // epilogue: divide by l, transpose 32c x 32qp tiles through LDS, store aot[n][c]
    float invl = 1.f / l_run;
    u16* ab = aot + (size_t)b * N_ * C_;
    int qg = lane >> 4, cd = lane & 15;
#pragma unroll
    for (int ct = 0; ct < 4; ++ct) {
        __syncthreads();
#pragma unroll
        for (int r = 0; r < 16; ++r)
            tls[wid][crow(r, hi)][r31] = acc[ct][r] * invl;
        __syncthreads();
#pragma unroll
        for (int it = 0; it < 8; ++it) {
            int qp = it * 4 + qg;
            u32 w = pk2(tls[wid][2 * cd][qp], tls[wid][2 * cd + 1][qp]);
            *reinterpret_cast<u32*>(ab + (size_t)(q0 + qp) * C_ + ch * 128 + ct * 32 + 2 * cd) = w;
        }
    }
}

// ---------------- outproj: Wo GEMM + BN + residual + relu ----------------
__global__ __launch_bounds__(256) void outproj(
    const u16* __restrict__ aot, const u16* __restrict__ wo,
    const float* __restrict__ scale, const float* __restrict__ shift,
    const float* __restrict__ x, float* __restrict__ out)
{
    int lane = threadIdx.x & 63, wid = threadIdx.x >> 6;
    int r31 = lane & 31, hi = lane >> 5;
    int b = blockIdx.z, n0 = blockIdx.x * 64, o0 = blockIdx.y * 64;
    int wo2 = wid >> 1, wn = wid & 1;
    const u16* ar = wo + (size_t)(o0 + wo2 * 32 + r31) * C_ + hi * 8;
    const u16* br = aot + ((size_t)b * N_ + n0 + wn * 32 + r31) * C_ + hi * 8;
    f32x16 acc;
#pragma unroll
    for (int r = 0; r < 16; ++r) acc[r] = 0.f;
#pragma unroll
    for (int ks = 0; ks < 16; ++ks)
        acc = __builtin_amdgcn_mfma_f32_32x32x16_bf16(ld8(ar + ks * 16), ld8(br + ks * 16), acc, 0, 0, 0);
    int n = n0 + wn * 32 + r31;
    const float* xb = x + (size_t)b * C_ * N_ + n;
    float* ob = out + (size_t)b * C_ * N_ + n;
#pragma unroll
    for (int r = 0; r < 16; ++r) {
        int o = o0 + wo2 * 32 + crow(r, hi);
        float val = acc[r] * scale[o] + shift[o] + xb[(size_t)o * N_];
        ob[(size_t)o * N_] = fmaxf(val, 0.f);
    }
}

extern "C" void kernel_launch(void* const* d_in, const int* in_sizes, int n_in,
                              void* d_out, int out_size, void* d_ws, size_t ws_size,
                              hipStream_t stream) {
    const float* x     = (const float*)d_in[0];
    const float* Wq    = (const float*)d_in[1];
    const float* bq    = (const float*)d_in[2];
    const float* Wk    = (const float*)d_in[3];
    const float* bk    = (const float*)d_in[4];
    const float* Wv    = (const float*)d_in[5];
    const float* bv    = (const float*)d_in[6];
    const float* Wo    = (const float*)d_in[7];
    const float* bo    = (const float*)d_in[8];
    const float* gamma = (const float*)d_in[9];
    const float* beta  = (const float*)d_in[10];
    const float* rmean = (const float*)d_in[11];
    const float* rvar  = (const float*)d_in[12];
    float* out = (float*)d_out;

    char* ws = (char*)d_ws;
    u16* xbt  = (u16*)(ws);                       // [B][N][C] bf16, 8 MB
    u16* vbuf = (u16*)(ws + (size_t)(8u << 20));  // [B][C][N] bf16, 8 MB
    u16* aot  = (u16*)(ws + (size_t)(16u << 20)); // [B][N][C] bf16, 8 MB
    u16* qkt  = (u16*)(ws + (size_t)(24u << 20)); // [B][N][64] bf16, 2 MB
    char* wsm = ws + (size_t)(26u << 20);
    u16* wqk  = (u16*)(wsm);                  // 64x256
    u16* wv_b = (u16*)(wsm + 32768);          // 256x256
    u16* wo_b = (u16*)(wsm + 32768 + 131072); // 256x256
    float* scl = (float*)(wsm + 32768 + 262144);
    float* shf = scl + 256;

    prep<<<dim3(578), dim3(256), 0, stream>>>(Wq, Wk, Wv, Wo, bo, gamma, beta, rmean, rvar,
                                              wqk, wv_b, wo_b, scl, shf);
    xpose<<<dim3(64, 4, 4), dim3(256), 0, stream>>>(x, xbt);
    proj_qkv<<<dim3(64, 5, 4), dim3(256), 0, stream>>>(xbt, wqk, wv_b, bq, bk, bv, qkt, vbuf);
    attn<<<dim3(64, 4), dim3(256), 0, stream>>>(qkt, vbuf, aot);
    outproj<<<dim3(64, 4, 4), dim3(256), 0, stream>>>(aot, wo_b, scl, shf, x, out);
}